// Round 2
// baseline (664.761 us; speedup 1.0000x reference)
//
#include <hip/hip_runtime.h>
#include <hip/hip_fp16.h>

#define NN 8192
#define MM 8192
#define FD 128
#define EDm 128
#define HD 64
#define NH 4

typedef float f32x4 __attribute__((ext_vector_type(4)));
typedef _Float16 h16x8 __attribute__((ext_vector_type(8)));
typedef _Float16 h16x4 __attribute__((ext_vector_type(4)));
typedef __fp16 fp16x2 __attribute__((ext_vector_type(2)));  // cvt_pkrtz native type

// w = mask ? (s+d>0 ? e^s e^d : e^{0.2s} e^{0.2d}) : 0 ; sign test via ed > e^{-s}
__device__ __forceinline__ float wmask(float edv, float ed2v, int msk,
                                       float es, float es2, float esi) {
  float p = (edv > esi) ? es * edv : es2 * ed2v;
  return __uint_as_float(__float_as_uint(p) & (unsigned)msk);
}

// vf[h][f] = sum_d Wf[h][f][d] * a[h][d]
__global__ void k_vf(const float* __restrict__ Wf, const float* __restrict__ a,
                     float* __restrict__ vf) {
  int t = threadIdx.x;            // 512 threads
  int h = t >> 7, f = t & 127;
  const float* w = Wf + (size_t)(h * FD + f) * HD;
  const float* av = a + h * HD;
  float s = 0.f;
#pragma unroll
  for (int d = 0; d < HD; ++d) s += w[d] * av[d];
  vf[h * FD + f] = s;
}

// esrc[h][n] = F0[n,:] . vf[h,:]
__global__ void k_esrc(const float* __restrict__ F0, const float* __restrict__ vf,
                       float* __restrict__ esrc) {
  int t = blockIdx.x * blockDim.x + threadIdx.x;  // 32768
  int n = t >> 2, h = t & 3;
  const float4* fr = (const float4*)(F0 + (size_t)n * FD);
  const float4* vr = (const float4*)(vf + h * FD);
  float s = 0.f;
#pragma unroll
  for (int i = 0; i < FD / 4; ++i) {
    float4 x = fr[i], y = vr[i];
    s += x.x * y.x + x.y * y.y + x.z * y.z + x.w * y.w;
  }
  esrc[h * NN + n] = s;
}

// One wave per (head, 4 m's): E1[h][m][d] fp32 -> E1T fp16 [h][d][m]; ed/ed2 tables.
__global__ void k_e1(const float* __restrict__ E0, const float* __restrict__ We,
                     const float* __restrict__ a, _Float16* __restrict__ E1T,
                     float* __restrict__ ed, float* __restrict__ ed2) {
  int wid = (blockIdx.x * blockDim.x + threadIdx.x) >> 6;
  int lane = threadIdx.x & 63;
  int h = wid >> 11;          // 2048 m-groups per head
  int mg = wid & 2047;
  int m = mg * 4;
  const float* we = We + (size_t)h * EDm * HD + lane;  // We[h][e][lane]
  const float* e0r = E0 + (size_t)m * EDm;
  float a0 = 0.f, a1 = 0.f, a2 = 0.f, a3 = 0.f;
#pragma unroll 4
  for (int e = 0; e < EDm; ++e) {
    float wv = we[e * HD];
    a0 += e0r[e] * wv;
    a1 += e0r[EDm + e] * wv;
    a2 += e0r[2 * EDm + e] * wv;
    a3 += e0r[3 * EDm + e] * wv;
  }
  h16x4 hv = {(_Float16)a0, (_Float16)a1, (_Float16)a2, (_Float16)a3};
  *(h16x4*)(E1T + (size_t)(h * HD + lane) * MM + m) = hv;
  // e_dst dot with a, wave-reduce over d (=lane)
  float av = a[h * HD + lane];
  float d0 = a0 * av, d1 = a1 * av, d2 = a2 * av, d3 = a3 * av;
#pragma unroll
  for (int o = 32; o; o >>= 1) {
    d0 += __shfl_xor(d0, o);
    d1 += __shfl_xor(d1, o);
    d2 += __shfl_xor(d2, o);
    d3 += __shfl_xor(d3, o);
  }
  if (lane == 0) {
    const float L2E = 1.4426950408889634f;
    ed[h * MM + m + 0] = exp2f(d0 * L2E);
    ed[h * MM + m + 1] = exp2f(d1 * L2E);
    ed[h * MM + m + 2] = exp2f(d2 * L2E);
    ed[h * MM + m + 3] = exp2f(d3 * L2E);
    ed2[h * MM + m + 0] = exp2f(0.2f * d0 * L2E);
    ed2[h * MM + m + 1] = exp2f(0.2f * d1 * L2E);
    ed2[h * MM + m + 2] = exp2f(0.2f * d2 * L2E);
    ed2[h * MM + m + 3] = exp2f(0.2f * d3 * L2E);
  }
}

// Main: 512 blocks x 256 thr. Block tile = 16 rows (n). Wave w = head w.
// k-loop over m in steps of 64 (2 MFMA-K). A mask staged to LDS once, shared
// across the 4 head-waves. B-frags (E1T fp16, 16B contiguous) direct from L2.
__global__ __launch_bounds__(256) void k_main(
    const int* __restrict__ A, const _Float16* __restrict__ E1T,
    const float* __restrict__ esrc, const float* __restrict__ ed,
    const float* __restrict__ ed2, float* __restrict__ out) {
  __shared__ int Am[16 * 68];        // +4 pad: breaks 16-way bank conflict
  __shared__ float EdS[NH * 64];
  __shared__ float Ed2S[NH * 64];
  __shared__ float Hp[NH][16][64];

  const int t = threadIdx.x;
  const int lane = t & 63;
  const int h = t >> 6;              // head
  const int col = lane & 15;
  const int quad = lane >> 4;
  const int n0 = blockIdx.x * 16;
  const float L2E = 1.4426950408889634f;

  float s = esrc[h * NN + n0 + col];
  float es = exp2f(s * L2E);
  float es2 = exp2f(0.2f * s * L2E);
  float esi = exp2f(-s * L2E);

  f32x4 acc[4] = {{0.f, 0.f, 0.f, 0.f}, {0.f, 0.f, 0.f, 0.f},
                  {0.f, 0.f, 0.f, 0.f}, {0.f, 0.f, 0.f, 0.f}};
  f32x4 accd = {0.f, 0.f, 0.f, 0.f};
  const h16x8 ones = {(_Float16)1.f, (_Float16)1.f, (_Float16)1.f, (_Float16)1.f,
                      (_Float16)1.f, (_Float16)1.f, (_Float16)1.f, (_Float16)1.f};

  // staging assignments
  const int arow = t >> 4;           // 0..15
  const int achk = t & 15;           // 16B chunk within 64-m window
  const int* aptr = A + (size_t)(n0 + arow) * MM + achk * 4;
  const float* edp = ed + (size_t)h * MM + lane;
  const float* ed2p = ed2 + (size_t)h * MM + lane;

  int4 areg = *(const int4*)aptr;    // tile 0 prefetch
  float edreg = *edp, ed2reg = *ed2p;

  const _Float16* bq = E1T + (size_t)(h * HD + col) * MM + quad * 8;

  for (int it = 0; it < 128; ++it) {
    const int k0 = it * 64;
    int4 mreg;
    mreg.x = areg.x > 0 ? -1 : 0;
    mreg.y = areg.y > 0 ? -1 : 0;
    mreg.z = areg.z > 0 ? -1 : 0;
    mreg.w = areg.w > 0 ? -1 : 0;
    *(int4*)&Am[arow * 68 + achk * 4] = mreg;
    EdS[h * 64 + lane] = edreg;
    Ed2S[h * 64 + lane] = ed2reg;
    __syncthreads();

    if (it < 127) {                  // prefetch next tile across compute
      areg = *(const int4*)(aptr + k0 + 64);
      edreg = edp[k0 + 64];
      ed2reg = ed2p[k0 + 64];
    }

    h16x8 bfr[2][4];
#pragma unroll
    for (int dt = 0; dt < 4; ++dt) {
#pragma unroll
      for (int kk = 0; kk < 2; ++kk)
        bfr[kk][dt] = *(const h16x8*)(bq + (size_t)dt * 16 * MM + k0 + kk * 32);
    }

#pragma unroll
    for (int kk = 0; kk < 2; ++kk) {
      const int kb = kk * 32 + quad * 8;
      const int* amrow = Am + col * 68 + kb;
      int4 m0 = *(const int4*)amrow;
      int4 m1 = *(const int4*)(amrow + 4);
      const float* er = EdS + h * 64 + kb;
      f32x4 e0 = *(const f32x4*)er;
      f32x4 e1 = *(const f32x4*)(er + 4);
      const float* fr2 = Ed2S + h * 64 + kb;
      f32x4 f0 = *(const f32x4*)fr2;
      f32x4 f1 = *(const f32x4*)(fr2 + 4);

      union { h16x8 v; fp16x2 p[4]; } af;
      af.p[0] = __builtin_amdgcn_cvt_pkrtz(wmask(e0[0], f0[0], m0.x, es, es2, esi),
                                           wmask(e0[1], f0[1], m0.y, es, es2, esi));
      af.p[1] = __builtin_amdgcn_cvt_pkrtz(wmask(e0[2], f0[2], m0.z, es, es2, esi),
                                           wmask(e0[3], f0[3], m0.w, es, es2, esi));
      af.p[2] = __builtin_amdgcn_cvt_pkrtz(wmask(e1[0], f1[0], m1.x, es, es2, esi),
                                           wmask(e1[1], f1[1], m1.y, es, es2, esi));
      af.p[3] = __builtin_amdgcn_cvt_pkrtz(wmask(e1[2], f1[2], m1.z, es, es2, esi),
                                           wmask(e1[3], f1[3], m1.w, es, es2, esi));

      acc[0] = __builtin_amdgcn_mfma_f32_16x16x32_f16(af.v, bfr[kk][0], acc[0], 0, 0, 0);
      acc[1] = __builtin_amdgcn_mfma_f32_16x16x32_f16(af.v, bfr[kk][1], acc[1], 0, 0, 0);
      acc[2] = __builtin_amdgcn_mfma_f32_16x16x32_f16(af.v, bfr[kk][2], acc[2], 0, 0, 0);
      acc[3] = __builtin_amdgcn_mfma_f32_16x16x32_f16(af.v, bfr[kk][3], acc[3], 0, 0, 0);
      accd = __builtin_amdgcn_mfma_f32_16x16x32_f16(af.v, ones, accd, 0, 0, 0);
    }
    __syncthreads();
  }

  // epilogue: h_prime = num/denom per head -> LDS; combine heads; row softmax
  f32x4 rd;
#pragma unroll
  for (int r2 = 0; r2 < 4; ++r2) rd[r2] = 1.0f / accd[r2];
#pragma unroll
  for (int dt = 0; dt < 4; ++dt) {
#pragma unroll
    for (int r2 = 0; r2 < 4; ++r2)
      Hp[h][quad * 4 + r2][dt * 16 + col] = acc[dt][r2] * rd[r2];
  }
  __syncthreads();

  for (int r = 0; r < 4; ++r) {
    int row = h * 4 + r;             // wave h handles rows h*4..h*4+3
    float v = 0.25f * (Hp[0][row][lane] + Hp[1][row][lane] +
                       Hp[2][row][lane] + Hp[3][row][lane]);
    float mx = v;
#pragma unroll
    for (int o = 32; o; o >>= 1) mx = fmaxf(mx, __shfl_xor(mx, o));
    float p = exp2f((v - mx) * L2E);
    float sm = p;
#pragma unroll
    for (int o = 32; o; o >>= 1) sm += __shfl_xor(sm, o);
    out[(size_t)(n0 + row) * HD + lane] = p / sm;
  }
}

extern "C" void kernel_launch(void* const* d_in, const int* in_sizes, int n_in,
                              void* d_out, int out_size, void* d_ws, size_t ws_size,
                              hipStream_t stream) {
  const float* F0 = (const float*)d_in[0];
  const float* E0 = (const float*)d_in[1];
  const int* A = (const int*)d_in[2];
  const float* Wf = (const float*)d_in[3];
  const float* We = (const float*)d_in[4];
  const float* a = (const float*)d_in[5];
  float* out = (float*)d_out;

  char* w = (char*)d_ws;
  float* esrc = (float*)w;  w += (size_t)NH * NN * 4;
  float* ed = (float*)w;    w += (size_t)NH * MM * 4;
  float* ed2 = (float*)w;   w += (size_t)NH * MM * 4;
  float* vf = (float*)w;    w += (size_t)NH * FD * 4;
  _Float16* E1T = (_Float16*)w;  w += (size_t)NH * HD * MM * 2;

  k_vf<<<1, 512, 0, stream>>>(Wf, a, vf);
  k_esrc<<<(NH * NN) / 256, 256, 0, stream>>>(F0, vf, esrc);
  k_e1<<<(NH * MM / 4) / 4, 256, 0, stream>>>(E0, We, a, E1T, ed, ed2);
  k_main<<<NN / 16, 256, 0, stream>>>(A, E1T, esrc, ed, ed2, out);
}

// Round 3
// 554.790 us; speedup vs baseline: 1.1982x; 1.1982x over previous
//
#include <hip/hip_runtime.h>
#include <hip/hip_fp16.h>

#define NN 8192
#define MM 8192
#define FD 128
#define EDm 128
#define HD 64
#define NH 4

#define MSPLIT 4
#define MRANGE (MM / MSPLIT)   // 2048
#define MSTEP 128
#define NITER (MRANGE / MSTEP) // 16
#define NTILE 32
#define AMS 132                // Am row stride in ints (128+4): conflict-free

typedef float f32x4 __attribute__((ext_vector_type(4)));
typedef _Float16 h16x8 __attribute__((ext_vector_type(8)));
typedef _Float16 h16x4 __attribute__((ext_vector_type(4)));
typedef __fp16 fp16x2 __attribute__((ext_vector_type(2)));

__device__ __forceinline__ float wmask(float edv, float ed2v, int a,
                                       float es, float es2, float esi) {
  float p = (edv > esi) ? es * edv : es2 * ed2v;
  return (a > 0) ? p : 0.0f;
}

// vf[h][f] = sum_d Wf[h][f][d] * a[h][d]
__global__ void k_vf(const float* __restrict__ Wf, const float* __restrict__ a,
                     float* __restrict__ vf) {
  int t = threadIdx.x;  // 512
  int h = t >> 7, f = t & 127;
  const float* w = Wf + (size_t)(h * FD + f) * HD;
  const float* av = a + h * HD;
  float s = 0.f;
#pragma unroll
  for (int d = 0; d < HD; ++d) s += w[d] * av[d];
  vf[h * FD + f] = s;
}

// esrc[h][n] = F0[n,:] . vf[h,:]
__global__ void k_esrc(const float* __restrict__ F0, const float* __restrict__ vf,
                       float* __restrict__ esrc) {
  int t = blockIdx.x * blockDim.x + threadIdx.x;  // 32768
  int n = t >> 2, h = t & 3;
  const float4* fr = (const float4*)(F0 + (size_t)n * FD);
  const float4* vr = (const float4*)(vf + h * FD);
  float s = 0.f;
#pragma unroll
  for (int i = 0; i < FD / 4; ++i) {
    float4 x = fr[i], y = vr[i];
    s += x.x * y.x + x.y * y.y + x.z * y.z + x.w * y.w;
  }
  esrc[h * NN + n] = s;
}

// E1[h][m][d] fp32 -> E1T fp16 [h][d][m]; ed/ed2 exp tables.
__global__ void k_e1(const float* __restrict__ E0, const float* __restrict__ We,
                     const float* __restrict__ a, _Float16* __restrict__ E1T,
                     float* __restrict__ ed, float* __restrict__ ed2) {
  int wid = (blockIdx.x * blockDim.x + threadIdx.x) >> 6;
  int lane = threadIdx.x & 63;
  int h = wid >> 11;
  int mg = wid & 2047;
  int m = mg * 4;
  const float* we = We + (size_t)h * EDm * HD + lane;
  const float* e0r = E0 + (size_t)m * EDm;
  float a0 = 0.f, a1 = 0.f, a2 = 0.f, a3 = 0.f;
#pragma unroll 4
  for (int e = 0; e < EDm; ++e) {
    float wv = we[e * HD];
    a0 += e0r[e] * wv;
    a1 += e0r[EDm + e] * wv;
    a2 += e0r[2 * EDm + e] * wv;
    a3 += e0r[3 * EDm + e] * wv;
  }
  h16x4 hv = {(_Float16)a0, (_Float16)a1, (_Float16)a2, (_Float16)a3};
  *(h16x4*)(E1T + (size_t)(h * HD + lane) * MM + m) = hv;
  float av = a[h * HD + lane];
  float d0 = a0 * av, d1 = a1 * av, d2 = a2 * av, d3 = a3 * av;
#pragma unroll
  for (int o = 32; o; o >>= 1) {
    d0 += __shfl_xor(d0, o);
    d1 += __shfl_xor(d1, o);
    d2 += __shfl_xor(d2, o);
    d3 += __shfl_xor(d3, o);
  }
  if (lane == 0) {
    const float L2E = 1.4426950408889634f;
    ed[h * MM + m + 0] = exp2f(d0 * L2E);
    ed[h * MM + m + 1] = exp2f(d1 * L2E);
    ed[h * MM + m + 2] = exp2f(d2 * L2E);
    ed[h * MM + m + 3] = exp2f(d3 * L2E);
    ed2[h * MM + m + 0] = exp2f(0.2f * d0 * L2E);
    ed2[h * MM + m + 1] = exp2f(0.2f * d1 * L2E);
    ed2[h * MM + m + 2] = exp2f(0.2f * d2 * L2E);
    ed2[h * MM + m + 3] = exp2f(0.2f * d3 * L2E);
  }
}

// Main: 1024 blocks x 256 thr. Block = (n-tile 32) x (m-split of 2048).
// Wave = head. 2 MFMA row-tiles per wave. m-step 128 per iteration.
__global__ __launch_bounds__(256, 3) void k_main(
    const int* __restrict__ A, const _Float16* __restrict__ E1T,
    const float* __restrict__ esrc, const float* __restrict__ ed,
    const float* __restrict__ ed2, float* __restrict__ pnum,
    float* __restrict__ pden) {
  __shared__ int Am[NTILE * AMS];   // 32 x 128 raw A ints (+4 pad)
  __shared__ float Ed[NH * 256];    // [h][ed 0..127 | ed2 128..255]

  const int t = threadIdx.x;
  const int lane = t & 63;
  const int h = t >> 6;
  const int col = lane & 15;
  const int quad = lane >> 4;

  const int b = blockIdx.x;
  const int xcdr = b & 7;                       // XCD residue: L2 locality
  const int split = xcdr >> 1;                  // split pinned to XCD pair
  const int ntile = ((b >> 3) << 1) | (xcdr & 1);
  const int n0 = ntile * NTILE;
  const int m0 = split * MRANGE;
  const float L2E = 1.4426950408889634f;

  float s0 = esrc[h * NN + n0 + col];
  float s1 = esrc[h * NN + n0 + 16 + col];
  float es0 = exp2f(s0 * L2E), eq0 = exp2f(0.2f * s0 * L2E), ei0 = exp2f(-s0 * L2E);
  float es1 = exp2f(s1 * L2E), eq1 = exp2f(0.2f * s1 * L2E), ei1 = exp2f(-s1 * L2E);

  f32x4 acc[2][4] = {};
  f32x4 accd[2] = {};
  const h16x8 ones = {(_Float16)1.f, (_Float16)1.f, (_Float16)1.f, (_Float16)1.f,
                      (_Float16)1.f, (_Float16)1.f, (_Float16)1.f, (_Float16)1.f};

  // A staging: thread -> row t>>3 (0..31), chunk t&7; 4 int4 per thread = 32x128
  const int arow = t >> 3;
  const int achk = t & 7;
  const int* aptr = A + (size_t)(n0 + arow) * MM + m0 + achk * 4;
  int* amw = Am + arow * AMS + achk * 4;
  // ed staging: lanes<32 ed, lanes>=32 ed2; 1 float4/lane = [h][256]
  const float* edsrc = ((lane < 32) ? ed : ed2) + (size_t)h * MM + m0 + (lane & 31) * 4;
  float* edw = Ed + h * 256 + (lane >> 5) * 128 + (lane & 31) * 4;

  int4 apf[4];
#pragma unroll
  for (int j = 0; j < 4; ++j) apf[j] = *(const int4*)(aptr + 32 * j);
  float4 edpf = *(const float4*)edsrc;

  const _Float16* bq = E1T + (size_t)(h * HD + col) * MM + m0 + quad * 8;

  for (int it = 0; it < NITER; ++it) {
    const int k0 = it * MSTEP;
#pragma unroll
    for (int j = 0; j < 4; ++j) *(int4*)(amw + 32 * j) = apf[j];
    *(float4*)edw = edpf;
    __syncthreads();

    if (it + 1 < NITER) {
#pragma unroll
      for (int j = 0; j < 4; ++j)
        apf[j] = *(const int4*)(aptr + k0 + MSTEP + 32 * j);
      edpf = *(const float4*)(edsrc + k0 + MSTEP);
    }

#pragma unroll
    for (int kk = 0; kk < 4; ++kk) {
      const int kb = kk * 32 + quad * 8;
      const int* am0 = Am + col * AMS + kb;
      const int* am1 = Am + (col + 16) * AMS + kb;
      int4 ma0 = *(const int4*)am0;
      int4 ma1 = *(const int4*)(am0 + 4);
      int4 mb0 = *(const int4*)am1;
      int4 mb1 = *(const int4*)(am1 + 4);
      const float* ep = Ed + h * 256 + kb;
      f32x4 e0 = *(const f32x4*)ep;
      f32x4 e1 = *(const f32x4*)(ep + 4);
      f32x4 f0 = *(const f32x4*)(ep + 128);
      f32x4 f1 = *(const f32x4*)(ep + 132);

      union { h16x8 v; fp16x2 p[4]; } af0, af1;
      af0.p[0] = __builtin_amdgcn_cvt_pkrtz(wmask(e0[0], f0[0], ma0.x, es0, eq0, ei0),
                                            wmask(e0[1], f0[1], ma0.y, es0, eq0, ei0));
      af0.p[1] = __builtin_amdgcn_cvt_pkrtz(wmask(e0[2], f0[2], ma0.z, es0, eq0, ei0),
                                            wmask(e0[3], f0[3], ma0.w, es0, eq0, ei0));
      af0.p[2] = __builtin_amdgcn_cvt_pkrtz(wmask(e1[0], f1[0], ma1.x, es0, eq0, ei0),
                                            wmask(e1[1], f1[1], ma1.y, es0, eq0, ei0));
      af0.p[3] = __builtin_amdgcn_cvt_pkrtz(wmask(e1[2], f1[2], ma1.z, es0, eq0, ei0),
                                            wmask(e1[3], f1[3], ma1.w, es0, eq0, ei0));
      af1.p[0] = __builtin_amdgcn_cvt_pkrtz(wmask(e0[0], f0[0], mb0.x, es1, eq1, ei1),
                                            wmask(e0[1], f0[1], mb0.y, es1, eq1, ei1));
      af1.p[1] = __builtin_amdgcn_cvt_pkrtz(wmask(e0[2], f0[2], mb0.z, es1, eq1, ei1),
                                            wmask(e0[3], f0[3], mb0.w, es1, eq1, ei1));
      af1.p[2] = __builtin_amdgcn_cvt_pkrtz(wmask(e1[0], f1[0], mb1.x, es1, eq1, ei1),
                                            wmask(e1[1], f1[1], mb1.y, es1, eq1, ei1));
      af1.p[3] = __builtin_amdgcn_cvt_pkrtz(wmask(e1[2], f1[2], mb1.z, es1, eq1, ei1),
                                            wmask(e1[3], f1[3], mb1.w, es1, eq1, ei1));

#pragma unroll
      for (int dt = 0; dt < 4; ++dt) {
        h16x8 bfr = *(const h16x8*)(bq + (size_t)dt * 16 * MM + k0 + kk * 32);
        acc[0][dt] = __builtin_amdgcn_mfma_f32_16x16x32_f16(af0.v, bfr, acc[0][dt], 0, 0, 0);
        acc[1][dt] = __builtin_amdgcn_mfma_f32_16x16x32_f16(af1.v, bfr, acc[1][dt], 0, 0, 0);
      }
      accd[0] = __builtin_amdgcn_mfma_f32_16x16x32_f16(af0.v, ones, accd[0], 0, 0, 0);
      accd[1] = __builtin_amdgcn_mfma_f32_16x16x32_f16(af1.v, ones, accd[1], 0, 0, 0);
    }
    __syncthreads();
  }

  // partial stores: pnum[(split*4+h)][n][d], pden[(split*4+h)][n]
  float* pn = pnum + (size_t)(split * NH + h) * NN * HD;
#pragma unroll
  for (int rt = 0; rt < 2; ++rt) {
#pragma unroll
    for (int dt = 0; dt < 4; ++dt) {
#pragma unroll
      for (int r2 = 0; r2 < 4; ++r2) {
        int n = n0 + rt * 16 + quad * 4 + r2;
        pn[(size_t)n * HD + dt * 16 + col] = acc[rt][dt][r2];
      }
    }
  }
  if (col == 0) {
    float* pd = pden + (size_t)(split * NH + h) * NN;
#pragma unroll
    for (int rt = 0; rt < 2; ++rt) {
#pragma unroll
      for (int r2 = 0; r2 < 4; ++r2)
        pd[n0 + rt * 16 + quad * 4 + r2] = accd[rt][r2];
    }
  }
}

// Combine splits, mean over heads, row softmax. Wave per n-row.
__global__ void k_comb(const float* __restrict__ pnum, const float* __restrict__ pden,
                       float* __restrict__ out) {
  int t = threadIdx.x;
  int lane = t & 63, w = t >> 6;
  int n = blockIdx.x * 4 + w;
  float v = 0.f;
#pragma unroll
  for (int h = 0; h < NH; ++h) {
    float num = 0.f, den = 0.f;
#pragma unroll
    for (int s = 0; s < MSPLIT; ++s) {
      num += pnum[((size_t)(s * NH + h) * NN + n) * HD + lane];
      den += pden[(size_t)(s * NH + h) * NN + n];
    }
    v += num / den;
  }
  v *= 0.25f;
  float mx = v;
#pragma unroll
  for (int o = 32; o; o >>= 1) mx = fmaxf(mx, __shfl_xor(mx, o));
  const float L2E = 1.4426950408889634f;
  float p = exp2f((v - mx) * L2E);
  float sm = p;
#pragma unroll
  for (int o = 32; o; o >>= 1) sm += __shfl_xor(sm, o);
  out[(size_t)n * HD + lane] = p / sm;
}

extern "C" void kernel_launch(void* const* d_in, const int* in_sizes, int n_in,
                              void* d_out, int out_size, void* d_ws, size_t ws_size,
                              hipStream_t stream) {
  const float* F0 = (const float*)d_in[0];
  const float* E0 = (const float*)d_in[1];
  const int* A = (const int*)d_in[2];
  const float* Wf = (const float*)d_in[3];
  const float* We = (const float*)d_in[4];
  const float* a = (const float*)d_in[5];
  float* out = (float*)d_out;

  char* w = (char*)d_ws;
  float* esrc = (float*)w;       w += (size_t)NH * NN * 4;
  float* ed = (float*)w;         w += (size_t)NH * MM * 4;
  float* ed2 = (float*)w;        w += (size_t)NH * MM * 4;
  float* vf = (float*)w;         w += (size_t)NH * FD * 4;
  _Float16* E1T = (_Float16*)w;  w += (size_t)NH * HD * MM * 2;
  float* pnum = (float*)w;       w += (size_t)MSPLIT * NH * NN * HD * 4;
  float* pden = (float*)w;       w += (size_t)MSPLIT * NH * NN * 4;

  k_vf<<<1, 512, 0, stream>>>(Wf, a, vf);
  k_esrc<<<(NH * NN) / 256, 256, 0, stream>>>(F0, vf, esrc);
  k_e1<<<(NH * MM / 4) / 4, 256, 0, stream>>>(E0, We, a, E1T, ed, ed2);
  k_main<<<256 * MSPLIT, 256, 0, stream>>>(A, E1T, esrc, ed, ed2, pnum, pden);
  k_comb<<<NN / 4, 256, 0, stream>>>(pnum, pden, out);
}

// Round 4
// 518.447 us; speedup vs baseline: 1.2822x; 1.0701x over previous
//
#include <hip/hip_runtime.h>
#include <hip/hip_fp16.h>

#define NN 8192
#define MM 8192
#define FD 128
#define EDm 128
#define HD 64
#define NH 4

#define MSPLIT 4
#define MRANGE (MM / MSPLIT)   // 2048
#define MSTEP 128
#define NITER (MRANGE / MSTEP) // 16
#define NTILE 32

typedef float f32x4 __attribute__((ext_vector_type(4)));
typedef _Float16 h16x8 __attribute__((ext_vector_type(8)));
typedef _Float16 h16x4 __attribute__((ext_vector_type(4)));
typedef int i32x4 __attribute__((ext_vector_type(4)));
typedef unsigned int u32;

// vf[h][f] = sum_d Wf[h][f][d] * a[h][d]
__global__ void k_vf(const float* __restrict__ Wf, const float* __restrict__ a,
                     float* __restrict__ vf) {
  int t = threadIdx.x;  // 512
  int h = t >> 7, f = t & 127;
  const float* w = Wf + (size_t)(h * FD + f) * HD;
  const float* av = a + h * HD;
  float s = 0.f;
#pragma unroll
  for (int d = 0; d < HD; ++d) s += w[d] * av[d];
  vf[h * FD + f] = s;
}

// esrc[h][n] = F0[n,:] . vf[h,:]
__global__ void k_esrc(const float* __restrict__ F0, const float* __restrict__ vf,
                       float* __restrict__ esrc) {
  int t = blockIdx.x * blockDim.x + threadIdx.x;  // 32768
  int n = t >> 2, h = t & 3;
  const float4* fr = (const float4*)(F0 + (size_t)n * FD);
  const float4* vr = (const float4*)(vf + h * FD);
  float s = 0.f;
#pragma unroll
  for (int i = 0; i < FD / 4; ++i) {
    float4 x = fr[i], y = vr[i];
    s += x.x * y.x + x.y * y.y + x.z * y.z + x.w * y.w;
  }
  esrc[h * NN + n] = s;
}

// E1 fp32 -> E1T fp16 [h][d][m]; edh = e^d, ed2h = e^{0.2 d} fp16 tables.
__global__ void k_e1(const float* __restrict__ E0, const float* __restrict__ We,
                     const float* __restrict__ a, _Float16* __restrict__ E1T,
                     _Float16* __restrict__ edh, _Float16* __restrict__ ed2h) {
  int wid = (blockIdx.x * blockDim.x + threadIdx.x) >> 6;
  int lane = threadIdx.x & 63;
  int h = wid >> 11;
  int mg = wid & 2047;
  int m = mg * 4;
  const float* we = We + (size_t)h * EDm * HD + lane;
  const float* e0r = E0 + (size_t)m * EDm;
  float a0 = 0.f, a1 = 0.f, a2 = 0.f, a3 = 0.f;
#pragma unroll 4
  for (int e = 0; e < EDm; ++e) {
    float wv = we[e * HD];
    a0 += e0r[e] * wv;
    a1 += e0r[EDm + e] * wv;
    a2 += e0r[2 * EDm + e] * wv;
    a3 += e0r[3 * EDm + e] * wv;
  }
  h16x4 hv = {(_Float16)a0, (_Float16)a1, (_Float16)a2, (_Float16)a3};
  *(h16x4*)(E1T + (size_t)(h * HD + lane) * MM + m) = hv;
  float av = a[h * HD + lane];
  float d0 = a0 * av, d1 = a1 * av, d2 = a2 * av, d3 = a3 * av;
#pragma unroll
  for (int o = 32; o; o >>= 1) {
    d0 += __shfl_xor(d0, o);
    d1 += __shfl_xor(d1, o);
    d2 += __shfl_xor(d2, o);
    d3 += __shfl_xor(d3, o);
  }
  if (lane == 0) {
    const float L2E = 1.4426950408889634f;
    edh[h * MM + m + 0] = (_Float16)exp2f(d0 * L2E);
    edh[h * MM + m + 1] = (_Float16)exp2f(d1 * L2E);
    edh[h * MM + m + 2] = (_Float16)exp2f(d2 * L2E);
    edh[h * MM + m + 3] = (_Float16)exp2f(d3 * L2E);
    ed2h[h * MM + m + 0] = (_Float16)exp2f(0.2f * d0 * L2E);
    ed2h[h * MM + m + 1] = (_Float16)exp2f(0.2f * d1 * L2E);
    ed2h[h * MM + m + 2] = (_Float16)exp2f(0.2f * d2 * L2E);
    ed2h[h * MM + m + 3] = (_Float16)exp2f(0.2f * d3 * L2E);
  }
}

__device__ __forceinline__ uint2 packmask(i32x4 a) {
  uint2 r;
  r.x = (a.x > 0 ? 0xffffu : 0u) | (a.y > 0 ? 0xffff0000u : 0u);
  r.y = (a.z > 0 ? 0xffffu : 0u) | (a.w > 0 ? 0xffff0000u : 0u);
  return r;
}

// Main: 1024 blocks x 256 thr. Block = 32 n-rows x 2048-m split. Wave = head.
// Per iter (128 m): B-frag loads FIRST (L2), then nt A/ed prefetch (HBM),
// then fp16-packed weight gen (mul+max+and) feeding MFMA.
__global__ __launch_bounds__(256) void k_main(
    const int* __restrict__ A, const _Float16* __restrict__ E1T,
    const float* __restrict__ esrc, const _Float16* __restrict__ edh,
    const _Float16* __restrict__ ed2h, float* __restrict__ pnum,
    float* __restrict__ pden) {
  __shared__ __align__(16) char smem[17408];
  u32* Amh = (u32*)smem;            // 32 rows x 68 dw (64 used): packed mask halves
  u32* EdU = (u32*)(smem + 8704);   // 4 heads x 136 dw: ed @0, ed2 @68
  float* Hpf = (float*)smem;        // epilogue reuse: [4][16][68]

  const int t = threadIdx.x;
  const int lane = t & 63;
  const int h = t >> 6;
  const int col = lane & 15;
  const int quad = lane >> 4;

  const int b = blockIdx.x;
  const int xcdr = b & 7;
  const int split = xcdr >> 1;      // split pinned to XCD pair (L2 locality)
  const int ntile = ((b >> 3) << 1) | (xcdr & 1);
  const int n0 = ntile * NTILE;
  const int m0 = split * MRANGE;
  const float L2E = 1.4426950408889634f;

  float s0 = esrc[h * NN + n0 + col];
  float s1 = esrc[h * NN + n0 + 16 + col];
  _Float16 e80 = (_Float16)exp2f(0.8f * s0 * L2E);
  _Float16 e81 = (_Float16)exp2f(0.8f * s1 * L2E);
  h16x8 es80 = {e80, e80, e80, e80, e80, e80, e80, e80};
  h16x8 es81 = {e81, e81, e81, e81, e81, e81, e81, e81};

  f32x4 acc[2][4] = {};
  f32x4 accd[2] = {};
  const h16x8 ones = {(_Float16)1.f, (_Float16)1.f, (_Float16)1.f, (_Float16)1.f,
                      (_Float16)1.f, (_Float16)1.f, (_Float16)1.f, (_Float16)1.f};

  // A staging: row t>>3, chunk t&7; ints achk*4 + 32j (j<4) within 128-window
  const int arow = t >> 3;
  const int achk = t & 7;
  const int* aptr = A + (size_t)(n0 + arow) * MM + m0 + achk * 4;
  u32* amw = Amh + arow * 68 + achk * 2;
  // ed staging: lanes<32 ed, lanes>=32 ed2; uint2 (4 halves) per lane per head
  const _Float16* edlane =
      ((lane < 32) ? edh : ed2h) + (size_t)h * MM + m0 + (lane & 31) * 4;
  u32* edw = EdU + h * 136 + ((lane >= 32) ? 68 : 0) + (lane & 31) * 2;

  i32x4 apf[4];
#pragma unroll
  for (int j = 0; j < 4; ++j)
    apf[j] = __builtin_nontemporal_load((const i32x4*)(aptr + 32 * j));
  uint2 edpf = *(const uint2*)edlane;

  const _Float16* bq = E1T + (size_t)(h * HD + col) * MM + m0 + quad * 8;

  for (int it = 0; it < NITER; ++it) {
    const int k0 = it * MSTEP;
#pragma unroll
    for (int j = 0; j < 4; ++j) *(uint2*)(amw + 16 * j) = packmask(apf[j]);
    *(uint2*)edw = edpf;
    __syncthreads();

    // 1) B-frag loads first (L2-resident E1T): consuming them never waits on A
    h16x8 bfr[16];
#pragma unroll
    for (int dt = 0; dt < 4; ++dt)
#pragma unroll
      for (int kk = 0; kk < 4; ++kk)
        bfr[dt * 4 + kk] =
            *(const h16x8*)(bq + (size_t)dt * 16 * MM + k0 + kk * 32);

    // 2) nt prefetch of next A window + ed tables (has whole compute to land)
    if (it + 1 < NITER) {
#pragma unroll
      for (int j = 0; j < 4; ++j)
        apf[j] = __builtin_nontemporal_load(
            (const i32x4*)(aptr + k0 + MSTEP + 32 * j));
      edpf = *(const uint2*)(edlane + k0 + MSTEP);
    }

    // 3) weights + MFMA
#pragma unroll
    for (int kk = 0; kk < 4; ++kk) {
      const int base = kk * 16 + quad * 4;
      uint4 ma = *(const uint4*)(Amh + col * 68 + base);
      uint4 mb = *(const uint4*)(Amh + (col + 16) * 68 + base);
      h16x8 edv = *(const h16x8*)(EdU + h * 136 + base);
      h16x8 e2v = *(const h16x8*)(EdU + h * 136 + 68 + base);
      h16x8 w0 = __builtin_elementwise_max(edv * es80, e2v);
      h16x8 w1 = __builtin_elementwise_max(edv * es81, e2v);
      union { h16x8 v; uint4 u; } a0, a1;
      a0.v = w0; a1.v = w1;
      a0.u.x &= ma.x; a0.u.y &= ma.y; a0.u.z &= ma.z; a0.u.w &= ma.w;
      a1.u.x &= mb.x; a1.u.y &= mb.y; a1.u.z &= mb.z; a1.u.w &= mb.w;
#pragma unroll
      for (int dt = 0; dt < 4; ++dt) {
        acc[0][dt] = __builtin_amdgcn_mfma_f32_16x16x32_f16(a0.v, bfr[dt * 4 + kk],
                                                            acc[0][dt], 0, 0, 0);
        acc[1][dt] = __builtin_amdgcn_mfma_f32_16x16x32_f16(a1.v, bfr[dt * 4 + kk],
                                                            acc[1][dt], 0, 0, 0);
      }
      accd[0] = __builtin_amdgcn_mfma_f32_16x16x32_f16(a0.v, ones, accd[0], 0, 0, 0);
      accd[1] = __builtin_amdgcn_mfma_f32_16x16x32_f16(a1.v, ones, accd[1], 0, 0, 0);
    }
    __syncthreads();
  }

  // Epilogue: transpose via LDS, coalesced nt float4 stores of partials.
  float* pn = pnum + (size_t)(split * NH + h) * NN * HD;
  float* pd = pden + (size_t)(split * NH + h) * NN;
#pragma unroll
  for (int rt = 0; rt < 2; ++rt) {
#pragma unroll
    for (int dt = 0; dt < 4; ++dt)
#pragma unroll
      for (int r2 = 0; r2 < 4; ++r2)
        Hpf[h * 1088 + (quad * 4 + r2) * 68 + dt * 16 + col] = acc[rt][dt][r2];
    if (col == 0) {
#pragma unroll
      for (int r2 = 0; r2 < 4; ++r2)
        Hpf[h * 1088 + (quad * 4 + r2) * 68 + 64] = accd[rt][r2];  // pad col
    }
    __syncthreads();
#pragma unroll
    for (int j = 0; j < 4; ++j) {
      int row = j * 4 + (lane >> 4);
      int c4 = lane & 15;
      f32x4 v = *(const f32x4*)(Hpf + h * 1088 + row * 68 + c4 * 4);
      __builtin_nontemporal_store(
          v, (f32x4*)(pn + (size_t)(n0 + rt * 16 + row) * HD + c4 * 4));
    }
    if (lane < 16) pd[n0 + rt * 16 + lane] = Hpf[h * 1088 + lane * 68 + 64];
    __syncthreads();
  }
}

// Combine splits, mean over heads, row softmax. Wave per n-row.
__global__ void k_comb(const float* __restrict__ pnum, const float* __restrict__ pden,
                       float* __restrict__ out) {
  int t = threadIdx.x;
  int lane = t & 63, w = t >> 6;
  int n = blockIdx.x * 4 + w;
  float v = 0.f;
#pragma unroll
  for (int h = 0; h < NH; ++h) {
    float num = 0.f, den = 0.f;
#pragma unroll
    for (int s = 0; s < MSPLIT; ++s) {
      num += pnum[((size_t)(s * NH + h) * NN + n) * HD + lane];
      den += pden[(size_t)(s * NH + h) * NN + n];
    }
    v += num / den;
  }
  v *= 0.25f;
  float mx = v;
#pragma unroll
  for (int o = 32; o; o >>= 1) mx = fmaxf(mx, __shfl_xor(mx, o));
  const float L2E = 1.4426950408889634f;
  float p = exp2f((v - mx) * L2E);
  float sm = p;
#pragma unroll
  for (int o = 32; o; o >>= 1) sm += __shfl_xor(sm, o);
  out[(size_t)n * HD + lane] = p / sm;
}

extern "C" void kernel_launch(void* const* d_in, const int* in_sizes, int n_in,
                              void* d_out, int out_size, void* d_ws, size_t ws_size,
                              hipStream_t stream) {
  const float* F0 = (const float*)d_in[0];
  const float* E0 = (const float*)d_in[1];
  const int* A = (const int*)d_in[2];
  const float* Wf = (const float*)d_in[3];
  const float* We = (const float*)d_in[4];
  const float* a = (const float*)d_in[5];
  float* out = (float*)d_out;

  char* w = (char*)d_ws;
  float* esrc = (float*)w;        w += (size_t)NH * NN * 4;
  _Float16* edh = (_Float16*)w;   w += (size_t)NH * MM * 2;
  _Float16* ed2h = (_Float16*)w;  w += (size_t)NH * MM * 2;
  float* vf = (float*)w;          w += (size_t)NH * FD * 4;
  _Float16* E1T = (_Float16*)w;   w += (size_t)NH * HD * MM * 2;
  float* pnum = (float*)w;        w += (size_t)MSPLIT * NH * NN * HD * 4;
  float* pden = (float*)w;        w += (size_t)MSPLIT * NH * NN * 4;

  k_vf<<<1, 512, 0, stream>>>(Wf, a, vf);
  k_esrc<<<(NH * NN) / 256, 256, 0, stream>>>(F0, vf, esrc);
  k_e1<<<(NH * MM / 4) / 4, 256, 0, stream>>>(E0, We, a, E1T, edh, ed2h);
  k_main<<<256 * MSPLIT, 256, 0, stream>>>(A, E1T, esrc, edh, ed2h, pnum, pden);
  k_comb<<<NN / 4, 256, 0, stream>>>(pnum, pden, out);
}